// Round 1
// baseline (24.264 us; speedup 1.0000x reference)
//
#include <hip/hip_runtime.h>
#include <math.h>

typedef _Float16 f16x8 __attribute__((ext_vector_type(8)));
typedef float    f32x4 __attribute__((ext_vector_type(4)));

#define SCRW 132   // 128 cols + 4 pad: rows stay 16B-aligned, banks de-aliased

__device__ __forceinline__ f32x4 mfma16(f16x8 a, f16x8 b, f32x4 c) {
  return __builtin_amdgcn_mfma_f32_16x16x32_f16(a, b, c, 0, 0, 0);
}

// Split 8 f32 (two float4) into f16 hi + f16 lo with hi+lo ~= x (rel ~2^-22)
__device__ __forceinline__ void splitA(f32x4 a0, f32x4 a1, f16x8& hi, f16x8& lo) {
#pragma unroll
  for (int j = 0; j < 4; ++j) {
    float x0 = a0[j], x1 = a1[j];
    _Float16 h0 = (_Float16)x0, h1 = (_Float16)x1;
    hi[j] = h0; hi[j + 4] = h1;
    lo[j]     = (_Float16)(x0 - (float)h0);
    lo[j + 4] = (_Float16)(x1 - (float)h1);
  }
}

// 8 consecutive f32 -> single-f16 B fragment (weights: rel err 2^-11, OK)
__device__ __forceinline__ f16x8 bfrag8(const float* p) {
  const f32x4* q = (const f32x4*)p;
  f32x4 w0 = q[0], w1 = q[1];
  f16x8 b;
#pragma unroll
  for (int j = 0; j < 4; ++j) { b[j] = (_Float16)w0[j]; b[j + 4] = (_Float16)w1[j]; }
  return b;
}

// Per-wave 16-sample tile. State kept in MFMA C-layout:
//   lane l holds [sample (l>>4)*4+r][unit cb*16 + (l&15)], r=0..3, cb=0..1.
// A-fragment assumed: row = l&15, k = (l>>4)*8 + j  (B uses the SAME k-map,
// so any within-K permutation of the true HW layout cancels).
__global__ __launch_bounds__(256) void mnist_cols(
    const float* __restrict__ img,  const float* __restrict__ Wff,
    const float* __restrict__ Wfb,  const float* __restrict__ Wvel,
    const float* __restrict__ Wc1,  const float* __restrict__ bc1,
    const float* __restrict__ Wc2,  const float* __restrict__ bc2,
    float* __restrict__ out) {
  __shared__ float scr_all[4][16 * SCRW];
  const int tid = threadIdx.x;
  const int wv = tid >> 6, l = tid & 63;
  const int g = l >> 4, c0 = l & 15, c1 = c0 + 16;
  float* scr = scr_all[wv];
  const int s0 = blockIdx.x * 64 + wv * 16;

  // ---- interpolation taps for this lane's two MC units (cols c0, c1) ----
  // pos = (i+0.5)*(784/32) - 0.5 = 24.5*i + 11.75 ; never clipped; hi = lo+1
  const float pos0 = 24.5f * (float)c0 + 11.75f;
  const float pos1 = 24.5f * (float)c1 + 11.75f;
  const int lo0 = (int)pos0, lo1 = (int)pos1;
  const float w0 = pos0 - (float)lo0, w1 = pos1 - (float)lo1;
  // transposed-flat index j -> flat index (j%28)*28 + j/28
  const int ta0 = (lo0 % 28) * 28 + lo0 / 28;
  const int tb0 = ((lo0 + 1) % 28) * 28 + (lo0 + 1) / 28;
  const int ta1 = (lo1 % 28) * 28 + lo1 / 28;
  const int tb1 = ((lo1 + 1) % 28) * 28 + (lo1 + 1) / 28;

  float sens[4][2], td[4][2];
#pragma unroll
  for (int r = 0; r < 4; ++r) {
    const float* base = img + (size_t)(s0 + g * 4 + r) * 784;
    float sa0 = base[lo0], sa1 = base[lo0 + 1];
    float sb0 = base[lo1], sb1 = base[lo1 + 1];
    float t00 = base[ta0], t01 = base[tb0];
    float t10 = base[ta1], t11 = base[tb1];
    sens[r][0] = (sa0 * (1.0f - w0) + sa1 * w0) * 80.0f;
    sens[r][1] = (sb0 * (1.0f - w1) + sb1 * w1) * 80.0f;
    td[r][0]   = (t00 * (1.0f - w0) + t01 * w0) * 40.0f;
    td[r][1]   = (t10 * (1.0f - w1) + t11 * w1) * 40.0f;
  }

  // ---- resident B-fragments: B[k][n] = W[n][k], n = nb*16 + (l&15) ----
  f16x8 bfb0 = bfrag8(Wfb + c0 * 32 + g * 8);
  f16x8 bfb1 = bfrag8(Wfb + c1 * 32 + g * 8);
  f16x8 bff0 = bfrag8(Wff + c0 * 32 + g * 8);
  f16x8 bff1 = bfrag8(Wff + c1 * 32 + g * 8);

  const float wva0 = Wvel[c0 * 2], wva1 = Wvel[c0 * 2 + 1];
  const float wvb0 = Wvel[c1 * 2], wvb1 = Wvel[c1 * 2 + 1];

  const f32x4 zero = {0.f, 0.f, 0.f, 0.f};
  f16x8 ahi, alo;

  // ---- y_fb = relu(topdown @ W_fb^T) ----
#pragma unroll
  for (int r = 0; r < 4; ++r) {
    int row = (g * 4 + r) * SCRW;
    scr[row + c0] = td[r][0];
    scr[row + c1] = td[r][1];
  }
  {
    const f32x4* ap = (const f32x4*)(scr + c0 * SCRW + g * 8);
    splitA(ap[0], ap[1], ahi, alo);
  }
  f32x4 afb0 = mfma16(alo, bfb0, mfma16(ahi, bfb0, zero));
  f32x4 afb1 = mfma16(alo, bfb1, mfma16(ahi, bfb1, zero));
  float yfb[4][2];
#pragma unroll
  for (int r = 0; r < 4; ++r) {
    yfb[r][0] = fmaxf(afb0[r], 0.f);
    yfb[r][1] = fmaxf(afb1[r], 0.f);
  }

  // ---- recurrence: eps_pos-eps_neg == sensory-pred, so
  //      d = sensory - r6@Wfb^T ; y_ff = relu(d@Wff^T) ; r6 += DT*(-r6+y_ff+y_fb+vel)
  float r6[4][2] = {};
  float d[4][2], yff[4][2];
  const float VX[3] = {0.2f, 0.0f, 0.15f};
  const float VY[3] = {0.0f, 0.2f, 0.15f};
#pragma unroll
  for (int v = 0; v < 3; ++v) {
    float vin[2];
    vin[0] = wva0 * VX[v] + wva1 * VY[v];
    vin[1] = wvb0 * VX[v] + wvb1 * VY[v];
#pragma unroll
    for (int st = 0; st < 3; ++st) {
      // pred = r6 @ Wfb^T (transpose r6 into A-frag via wave-local LDS)
#pragma unroll
      for (int r = 0; r < 4; ++r) {
        int row = (g * 4 + r) * SCRW;
        scr[row + c0] = r6[r][0];
        scr[row + c1] = r6[r][1];
      }
      {
        const f32x4* ap = (const f32x4*)(scr + c0 * SCRW + g * 8);
        splitA(ap[0], ap[1], ahi, alo);
      }
      f32x4 p0 = mfma16(alo, bfb0, mfma16(ahi, bfb0, zero));
      f32x4 p1 = mfma16(alo, bfb1, mfma16(ahi, bfb1, zero));
#pragma unroll
      for (int r = 0; r < 4; ++r) {
        d[r][0] = sens[r][0] - p0[r];
        d[r][1] = sens[r][1] - p1[r];
      }
      // y_ff = relu(d @ Wff^T)
#pragma unroll
      for (int r = 0; r < 4; ++r) {
        int row = (g * 4 + r) * SCRW;
        scr[row + c0] = d[r][0];
        scr[row + c1] = d[r][1];
      }
      {
        const f32x4* ap = (const f32x4*)(scr + c0 * SCRW + g * 8);
        splitA(ap[0], ap[1], ahi, alo);
      }
      f32x4 q0 = mfma16(alo, bff0, mfma16(ahi, bff0, zero));
      f32x4 q1 = mfma16(alo, bff1, mfma16(ahi, bff1, zero));
#pragma unroll
      for (int r = 0; r < 4; ++r) {
        yff[r][0] = fmaxf(q0[r], 0.f);
        yff[r][1] = fmaxf(q1[r], 0.f);
#pragma unroll
        for (int cb = 0; cb < 2; ++cb)
          r6[r][cb] = r6[r][cb] + 0.1f * (yff[r][cb] - r6[r][cb] + yfb[r][cb] + vin[cb]);
      }
    }
  }

  // ---- feature = [y_ff | y_fb | r6 | |d|]  (eps_pos+eps_neg == |d|) ----
#pragma unroll
  for (int r = 0; r < 4; ++r) {
    int row = (g * 4 + r) * SCRW;
    scr[row +      c0] = yff[r][0];        scr[row +      c1] = yff[r][1];
    scr[row + 32 + c0] = yfb[r][0];        scr[row + 32 + c1] = yfb[r][1];
    scr[row + 64 + c0] = r6[r][0];         scr[row + 64 + c1] = r6[r][1];
    scr[row + 96 + c0] = fabsf(d[r][0]);   scr[row + 96 + c1] = fabsf(d[r][1]);
  }
  f32x4 acc0 = zero, acc1 = zero, acc2 = zero, acc3 = zero;
#pragma unroll
  for (int kb = 0; kb < 4; ++kb) {
    const f32x4* ap = (const f32x4*)(scr + c0 * SCRW + kb * 32 + g * 8);
    f16x8 fhi, flo;
    splitA(ap[0], ap[1], fhi, flo);
    const int ko = kb * 32 + g * 8;
    f16x8 b0 = bfrag8(Wc1 + (size_t)(0 * 16 + c0) * 128 + ko);
    f16x8 b1 = bfrag8(Wc1 + (size_t)(1 * 16 + c0) * 128 + ko);
    f16x8 b2 = bfrag8(Wc1 + (size_t)(2 * 16 + c0) * 128 + ko);
    f16x8 b3 = bfrag8(Wc1 + (size_t)(3 * 16 + c0) * 128 + ko);
    acc0 = mfma16(flo, b0, mfma16(fhi, b0, acc0));
    acc1 = mfma16(flo, b1, mfma16(fhi, b1, acc1));
    acc2 = mfma16(flo, b2, mfma16(fhi, b2, acc2));
    acc3 = mfma16(flo, b3, mfma16(fhi, b3, acc3));
  }
  // bias + exact gelu
  float h[4][4];
  const float B0 = bc1[c0], B1 = bc1[16 + c0], B2 = bc1[32 + c0], B3 = bc1[48 + c0];
#pragma unroll
  for (int r = 0; r < 4; ++r) {
    float x0 = acc0[r] + B0, x1 = acc1[r] + B1, x2 = acc2[r] + B2, x3 = acc3[r] + B3;
    h[r][0] = 0.5f * x0 * (1.0f + erff(x0 * 0.70710678118654752f));
    h[r][1] = 0.5f * x1 * (1.0f + erff(x1 * 0.70710678118654752f));
    h[r][2] = 0.5f * x2 * (1.0f + erff(x2 * 0.70710678118654752f));
    h[r][3] = 0.5f * x3 * (1.0f + erff(x3 * 0.70710678118654752f));
  }

  // ---- logits = h @ Wc2^T + bc2 ----
#pragma unroll
  for (int r = 0; r < 4; ++r) {
    int row = (g * 4 + r) * SCRW;
#pragma unroll
    for (int nb = 0; nb < 4; ++nb) scr[row + nb * 16 + c0] = h[r][nb];
  }
  f32x4 accL = zero;
#pragma unroll
  for (int kb = 0; kb < 2; ++kb) {
    const f32x4* ap = (const f32x4*)(scr + c0 * SCRW + kb * 32 + g * 8);
    f16x8 hhi, hlo;
    splitA(ap[0], ap[1], hhi, hlo);
    f16x8 b;
    if (c0 < 10) {
      b = bfrag8(Wc2 + (size_t)c0 * 64 + kb * 32 + g * 8);
    } else {
#pragma unroll
      for (int j = 0; j < 8; ++j) b[j] = (_Float16)0.f;
    }
    accL = mfma16(hlo, b, mfma16(hhi, b, accL));
  }
  if (c0 < 10) {
    const float bb = bc2[c0];
#pragma unroll
    for (int r = 0; r < 4; ++r)
      out[(size_t)(s0 + g * 4 + r) * 10 + c0] = accL[r] + bb;
  }
}

extern "C" void kernel_launch(void* const* d_in, const int* in_sizes, int n_in,
                              void* d_out, int out_size, void* d_ws, size_t ws_size,
                              hipStream_t stream) {
  const float* img  = (const float*)d_in[0];
  const float* Wff  = (const float*)d_in[1];   // NOTE: W_ff is input 1, W_fb is input 2
  const float* Wfb  = (const float*)d_in[2];
  const float* Wvel = (const float*)d_in[3];
  const float* Wc1  = (const float*)d_in[4];
  const float* bc1  = (const float*)d_in[5];
  const float* Wc2  = (const float*)d_in[6];
  const float* bc2  = (const float*)d_in[7];
  float* out = (float*)d_out;
  const int B = in_sizes[0] / 784;     // 16384
  const int grid = B / 64;             // 64 samples / block (4 waves x 16)
  hipLaunchKernelGGL(mnist_cols, dim3(grid), dim3(256), 0, stream,
                     img, Wff, Wfb, Wvel, Wc1, bc1, Wc2, bc2, out);
}